// Round 13
// baseline (109.557 us; speedup 1.0000x reference)
//
#include <hip/hip_runtime.h>
#include <math.h>

#define K_INST 256
#define ATTRACTION_W 1.0f
#define REPULSION_W 1.0f
#define BETA_POS_W 1.0f
#define BETA_NEG_W 0.5f

typedef float f32x4 __attribute__((ext_vector_type(4)));
typedef int i32x4 __attribute__((ext_vector_type(4)));

__device__ inline float softplusf(float x) {
    return fmaxf(x, 0.f) + log1pf(expf(-fabsf(x)));
}

__device__ inline float waveReduceSumF(float v) {
    for (int o = 32; o; o >>= 1) v += __shfl_xor(v, o);
    return v;
}
__device__ inline int waveReduceSumI(int v) {
    for (int o = 32; o; o >>= 1) v += __shfl_xor(v, o);
    return v;
}

// 4 points per thread + sid histogram (seg_cnt). grid (N/1024, B), block 256.
__global__ void stats_kernel(const float* __restrict__ beta,
                             const int* __restrict__ sid,
                             const int* __restrict__ is_cp,
                             int* fc_rev,
                             float* pos_sum, float* neg_sum,
                             int* seg_cnt,
                             int* cpv_cnt, int* noncp_cnt, int* valid_cnt,
                             int N) {
    int b = blockIdx.y;
    int base = (blockIdx.x * blockDim.x + threadIdx.x) * 4;
    const float* betaB = beta + (size_t)b * N;
    const int* sidB = sid + (size_t)b * N;
    const int* cpB = is_cp + (size_t)b * N;

    __shared__ int hist[K_INST];
    for (int k = threadIdx.x; k < K_INST; k += blockDim.x) hist[k] = 0;
    __syncthreads();

    i32x4 s4 = *(const i32x4*)(sidB + base);
    i32x4 c4 = *(const i32x4*)(cpB + base);
    f32x4 x4 = *(const f32x4*)(betaB + base);

    float pos = 0.f, neg = 0.f;
    int c_cpv = 0, c_non = 0, c_val = 0;
    #pragma unroll
    for (int e = 0; e < 4; ++e) {
        int s = s4[e], cp = c4[e];
        float x = x4[e];
        bool valid = s >= 0;
        bool cpv = cp && valid;
        if (valid) atomicAdd(&hist[s], 1);
        if (cpv) {
            pos += softplusf(-x);
            c_cpv++;
            atomicMax(&fc_rev[b * K_INST + s], N - (base + e));
        }
        if (!cp) {
            neg += softplusf(x);
            c_non++;
        }
        c_val += valid ? 1 : 0;
    }

    __shared__ float sf[2][4];
    __shared__ int si[3][4];
    pos = waveReduceSumF(pos);
    neg = waveReduceSumF(neg);
    c_cpv = waveReduceSumI(c_cpv);
    c_non = waveReduceSumI(c_non);
    c_val = waveReduceSumI(c_val);
    int wave = threadIdx.x >> 6, lane = threadIdx.x & 63;
    if (lane == 0) {
        sf[0][wave] = pos; sf[1][wave] = neg;
        si[0][wave] = c_cpv; si[1][wave] = c_non; si[2][wave] = c_val;
    }
    __syncthreads();
    if (threadIdx.x == 0) {
        float p = sf[0][0] + sf[0][1] + sf[0][2] + sf[0][3];
        float n = sf[1][0] + sf[1][1] + sf[1][2] + sf[1][3];
        int a = si[0][0] + si[0][1] + si[0][2] + si[0][3];
        int c = si[1][0] + si[1][1] + si[1][2] + si[1][3];
        int v = si[2][0] + si[2][1] + si[2][2] + si[2][3];
        if (p != 0.f) atomicAdd(&pos_sum[b], p);
        if (n != 0.f) atomicAdd(&neg_sum[b], n);
        if (a) atomicAdd(&cpv_cnt[b], a);
        if (c) atomicAdd(&noncp_cnt[b], c);
        if (v) atomicAdd(&valid_cnt[b], v);
    }
    for (int k = threadIdx.x; k < K_INST; k += blockDim.x) {
        int h = hist[k];
        if (h) atomicAdd(&seg_cnt[b * K_INST + k], h);
    }
}

// counting-sort scatter: order[b][slot] = (i<<8)|s, segment-major.
// Also writes seg_start (exclusive prefix of seg_cnt). grid (N/1024, B).
__global__ void scatter_kernel(const int* __restrict__ sid,
                               const int* __restrict__ seg_cnt,
                               int* cursor, int* order, int* seg_start, int N) {
    int b = blockIdx.y;
    int base = (blockIdx.x * blockDim.x + threadIdx.x) * 4;
    const int* sidB = sid + (size_t)b * N;
    int* orderB = order + (size_t)b * N;

    __shared__ int lhist[K_INST];
    __shared__ int lcnt[K_INST];
    __shared__ int lbase[K_INST];
    __shared__ int scanA[K_INST];
    __shared__ int scanB[K_INST];
    __shared__ int segS[K_INST];

    int t = threadIdx.x;
    lhist[t] = 0; lcnt[t] = 0;
    __syncthreads();

    i32x4 s4 = *(const i32x4*)(sidB + base);
    #pragma unroll
    for (int e = 0; e < 4; ++e) {
        if (s4[e] >= 0) atomicAdd(&lhist[s4[e]], 1);
    }
    __syncthreads();

    // exclusive prefix of global seg_cnt
    int myCnt = seg_cnt[b * K_INST + t];
    scanA[t] = myCnt;
    __syncthreads();
    int* src = scanA; int* dst = scanB;
    #pragma unroll
    for (int off = 1; off < K_INST; off <<= 1) {
        int v = src[t] + ((t >= off) ? src[t - off] : 0);
        dst[t] = v;
        __syncthreads();
        int* tmp = src; src = dst; dst = tmp;
    }
    segS[t] = src[t] - myCnt;   // exclusive prefix
    if (blockIdx.x == 0) seg_start[b * K_INST + t] = segS[t];
    // reserve this block's range in each segment
    int h = lhist[t];
    lbase[t] = (h > 0) ? atomicAdd(&cursor[b * K_INST + t], h) : 0;
    __syncthreads();

    #pragma unroll
    for (int e = 0; e < 4; ++e) {
        int s = s4[e];
        if (s >= 0) {
            int r = atomicAdd(&lcnt[s], 1);
            int slot = segS[s] + lbase[s] + r;
            orderB[slot] = ((base + e) << 8) | s;
        }
    }
}

// one block per (k, b), 64 threads. writes row + transposed scatter.
__global__ void gather_kernel(const float* __restrict__ embed,
                              const int* __restrict__ fc_rev,
                              float* __restrict__ cp_emb,
                              float* __restrict__ cp_embT, int N) {
    int b = blockIdx.y;
    int k = blockIdx.x;
    int src = N - fc_rev[b * K_INST + k];
    if (src >= N) src = N - 1;
    int lane = threadIdx.x;
    const float* embB = embed + (size_t)b * N * 256;
    f32x4 v = ((const f32x4*)(embB + (size_t)src * 256))[lane];
    ((f32x4*)(cp_emb + ((size_t)b * K_INST + k) * 256))[lane] = v;
    float* T = cp_embT + (size_t)b * K_INST * 256;
    int d = lane * 4;
    T[(size_t)(d + 0) * 256 + k] = v[0];
    T[(size_t)(d + 1) * 256 + k] = v[1];
    T[(size_t)(d + 2) * 256 + k] = v[2];
    T[(size_t)(d + 3) * 256 + k] = v[3];
}

// 512-thread blocks. blockIdx.x < 256: one segment each (norm expansion,
// register accumulation, no c-loads in hot loop). blockIdx.x 256..271:
// repulsion, 16 i-rows each.
__global__ void attraction_repulsion_kernel(
        const float* __restrict__ embed,
        const int* __restrict__ order,
        const int* __restrict__ seg_start,
        const int* __restrict__ seg_cnt,
        const int* __restrict__ fc_rev,
        const float* __restrict__ cp_emb,
        const float* __restrict__ cp_embT,
        float* seg_att, float* rep_sum, int N) {
    int b = blockIdx.y;
    __shared__ __align__(16) float smemF[16896 / 4 + 16];  // union
    const float* cpB = cp_emb + (size_t)b * K_INST * 256;

    if (blockIdx.x < K_INST) {
        // ---------------- attraction: one segment ----------------
        int s = blockIdx.x;
        int cnt = seg_cnt[b * K_INST + s];
        float* vec_lds = smemF;            // [256]
        float* sq_lds = smemF + 256;       // scalar
        if (threadIdx.x < 256) vec_lds[threadIdx.x] = 0.f;
        if (threadIdx.x == 256 % 512) ;    // no-op
        if (threadIdx.x == 0) *sq_lds = 0.f;
        __syncthreads();

        int wave = threadIdx.x >> 6;
        int lane = threadIdx.x & 63;
        if (cnt > 0) {
            int start = seg_start[b * K_INST + s];
            int chunk = (cnt + 7) >> 3;
            int w0 = start + wave * chunk;
            int w1 = min(w0 + chunk, start + cnt);
            const int* ordB = order + (size_t)b * N;
            const float* embB = embed + (size_t)b * N * 256;

            f32x4 acc = {0.f, 0.f, 0.f, 0.f};
            float sq = 0.f;
            for (int p = w0; p < w1; p += 4) {
                int n = w1 - p;
                int e0 = ordB[p];
                int e1 = (n > 1) ? ordB[p + 1] : -1;
                int e2 = (n > 2) ? ordB[p + 2] : -1;
                int e3 = (n > 3) ? ordB[p + 3] : -1;
                f32x4 v0 = __builtin_nontemporal_load(
                    (const f32x4*)(embB + ((size_t)(e0 >> 8) << 8) + lane * 4));
                acc += v0;
                sq += v0[0] * v0[0] + v0[1] * v0[1] + v0[2] * v0[2] + v0[3] * v0[3];
                if (e1 >= 0) {
                    f32x4 v = __builtin_nontemporal_load(
                        (const f32x4*)(embB + ((size_t)(e1 >> 8) << 8) + lane * 4));
                    acc += v;
                    sq += v[0] * v[0] + v[1] * v[1] + v[2] * v[2] + v[3] * v[3];
                }
                if (e2 >= 0) {
                    f32x4 v = __builtin_nontemporal_load(
                        (const f32x4*)(embB + ((size_t)(e2 >> 8) << 8) + lane * 4));
                    acc += v;
                    sq += v[0] * v[0] + v[1] * v[1] + v[2] * v[2] + v[3] * v[3];
                }
                if (e3 >= 0) {
                    f32x4 v = __builtin_nontemporal_load(
                        (const f32x4*)(embB + ((size_t)(e3 >> 8) << 8) + lane * 4));
                    acc += v;
                    sq += v[0] * v[0] + v[1] * v[1] + v[2] * v[2] + v[3] * v[3];
                }
            }
            // flush: lane owns dims lane*4..lane*4+3 (8-way wave aliasing only)
            atomicAdd(&vec_lds[lane * 4 + 0], acc[0]);
            atomicAdd(&vec_lds[lane * 4 + 1], acc[1]);
            atomicAdd(&vec_lds[lane * 4 + 2], acc[2]);
            atomicAdd(&vec_lds[lane * 4 + 3], acc[3]);
            sq = waveReduceSumF(sq);
            if (lane == 0) atomicAdd(sq_lds, sq);
        }
        __syncthreads();
        if (threadIdx.x < 64) {
            float att = 0.f;
            if (cnt > 0) {
                int lane2 = threadIdx.x;
                f32x4 v = *(const f32x4*)(vec_lds + lane2 * 4);
                f32x4 c = *(const f32x4*)(cpB + (size_t)s * 256 + lane2 * 4);
                float dp = v[0] * c[0] + v[1] * c[1] + v[2] * c[2] + v[3] * c[3];
                float cn = c[0] * c[0] + c[1] * c[1] + c[2] * c[2] + c[3] * c[3];
                #pragma unroll
                for (int o = 1; o <= 32; o <<= 1) {
                    dp += __shfl_xor(dp, o);
                    cn += __shfl_xor(cn, o);
                }
                if (lane2 == 0) {
                    float sqv = *sq_lds;
                    att = (sqv - 2.f * dp + (float)cnt * cn) / (float)cnt;
                }
            }
            if (threadIdx.x == 0) seg_att[b * K_INST + s] = att;
        }
    } else {
        // ---------------- repulsion: 16 i-rows per block ----------------
        float (*srow)[264] = (float(*)[264])smemF;      // [16][264]
        float* sf = smemF + 16 * 264;                   // [8]
        const int* fcB = fc_rev + b * K_INST;
        int i0 = (blockIdx.x - K_INST) * 16;
        const float* T = cp_embT + (size_t)b * K_INST * 256;
        {
            int row = threadIdx.x >> 5, cc = (threadIdx.x & 31) * 8;
            f32x4 a = *(const f32x4*)(cpB + (size_t)(i0 + row) * 256 + cc);
            f32x4 bv = *(const f32x4*)(cpB + (size_t)(i0 + row) * 256 + cc + 4);
            srow[row][cc + 0] = a[0]; srow[row][cc + 1] = a[1];
            srow[row][cc + 2] = a[2]; srow[row][cc + 3] = a[3];
            srow[row][cc + 4] = bv[0]; srow[row][cc + 5] = bv[1];
            srow[row][cc + 6] = bv[2]; srow[row][cc + 7] = bv[3];
        }
        __syncthreads();

        int j = threadIdx.x & 255;
        int half = threadIdx.x >> 8;   // 0/1
        bool has_j = fcB[j] > 0;
        float acc[8] = {0.f, 0.f, 0.f, 0.f, 0.f, 0.f, 0.f, 0.f};
        for (int d = 0; d < 256; d += 2) {
            float v0 = T[(size_t)d * 256 + j];
            float v1 = T[(size_t)(d + 1) * 256 + j];
            #pragma unroll
            for (int r = 0; r < 8; ++r) {
                int row = half * 8 + r;
                float f0 = srow[row][d] - v0;
                float f1 = srow[row][d + 1] - v1;
                acc[r] += f0 * f0 + f1 * f1;
            }
        }
        float val = 0.f;
        #pragma unroll
        for (int r = 0; r < 8; ++r) {
            bool has_i = fcB[i0 + half * 8 + r] > 0;
            if (has_i && has_j) val += expf(-acc[r]);
        }
        val = waveReduceSumF(val);
        int wave = threadIdx.x >> 6, lane = threadIdx.x & 63;
        if (lane == 0) sf[wave] = val;
        __syncthreads();
        if (threadIdx.x == 0) {
            float t = 0.f;
            #pragma unroll
            for (int w = 0; w < 8; ++w) t += sf[w];
            atomicAdd(&rep_sum[b], t);
        }
    }
}

__global__ void final_kernel(const int* __restrict__ fc_rev,
                             const float* __restrict__ seg_att,
                             const int* __restrict__ seg_cnt,
                             const float* __restrict__ pos_sum,
                             const float* __restrict__ neg_sum,
                             const float* __restrict__ rep_sum,
                             const int* __restrict__ cpv_cnt,
                             const int* __restrict__ noncp_cnt,
                             const int* __restrict__ valid_cnt,
                             float* out, int N, int B) {
    __shared__ float s_att[4];
    __shared__ int s_m[4];
    float loss_sum = 0.f;
    int ok_cnt = 0;
    int wave = threadIdx.x >> 6, lane = threadIdx.x & 63;
    for (int b = 0; b < B; ++b) {
        int k = threadIdx.x;
        int has = (fc_rev[b * K_INST + k] > 0) ? 1 : 0;
        int cnt = seg_cnt[b * K_INST + k];
        float att = (has && cnt > 0) ? seg_att[b * K_INST + k] : 0.f;
        att = waveReduceSumF(att);
        has = waveReduceSumI(has);
        if (lane == 0) { s_att[wave] = att; s_m[wave] = has; }
        __syncthreads();
        if (threadIdx.x == 0) {
            float attraction = (s_att[0] + s_att[1] + s_att[2] + s_att[3]) * ATTRACTION_W;
            int M = s_m[0] + s_m[1] + s_m[2] + s_m[3];
            float pos = pos_sum[b] / fmaxf((float)cpv_cnt[b], 1.f);
            float neg = neg_sum[b] / fmaxf((float)noncp_cnt[b], 1.f);
            float beta_loss = BETA_POS_W * pos + BETA_NEG_W * neg;
            float rep = 0.f;
            if (M > 1) {
                float mm = (float)M * (float)M;
                rep = (rep_sum[b] / fmaxf(mm, 1.f)) * REPULSION_W;
            }
            float loss = beta_loss + attraction + rep;
            bool ok = (valid_cnt[b] > 0) && (cpv_cnt[b] > 0);
            if (ok) { loss_sum += loss; ok_cnt += 1; }
        }
        __syncthreads();
    }
    if (threadIdx.x == 0) {
        out[0] = (ok_cnt > 0) ? (loss_sum / (float)ok_cnt) : 0.f;
    }
}

extern "C" void kernel_launch(void* const* d_in, const int* in_sizes, int n_in,
                              void* d_out, int out_size, void* d_ws, size_t ws_size,
                              hipStream_t stream) {
    const float* beta  = (const float*)d_in[0];
    const float* embed = (const float*)d_in[1];
    const int* sid     = (const int*)d_in[2];
    const int* is_cp   = (const int*)d_in[3];
    float* out = (float*)d_out;

    const int N = 65536;
    const int B = in_sizes[0] / N;
    (void)n_in; (void)out_size; (void)ws_size;

    char* ws = (char*)d_ws;
    int*   fc_rev    = (int*)(ws + 0);          // B*K, 0 = no CP
    int*   seg_cnt   = (int*)(ws + 4096);       // B*K
    int*   cursor    = (int*)(ws + 8192);       // B*K
    int*   seg_start = (int*)(ws + 12288);      // B*K
    float* seg_att   = (float*)(ws + 16384);    // B*K
    float* pos_sum   = (float*)(ws + 20480);
    float* neg_sum   = (float*)(ws + 20544);
    float* rep_sum   = (float*)(ws + 20608);
    int*   cpv_cnt   = (int*)(ws + 20672);
    int*   noncp_cnt = (int*)(ws + 20736);
    int*   valid_cnt = (int*)(ws + 20800);
    int*   order     = (int*)(ws + 24576);      // B*N ints (1 MiB)
    float* cp_emb    = (float*)(ws + 24576 + (size_t)B * N * 4);
    float* cp_embT   = cp_emb + (size_t)B * K_INST * 256;

    hipMemsetAsync(ws, 0, 24576, stream);

    stats_kernel<<<dim3(N / 1024, B), dim3(256), 0, stream>>>(
        beta, sid, is_cp, fc_rev, pos_sum, neg_sum, seg_cnt,
        cpv_cnt, noncp_cnt, valid_cnt, N);

    scatter_kernel<<<dim3(N / 1024, B), dim3(256), 0, stream>>>(
        sid, seg_cnt, cursor, order, seg_start, N);

    gather_kernel<<<dim3(K_INST, B), dim3(64), 0, stream>>>(
        embed, fc_rev, cp_emb, cp_embT, N);

    attraction_repulsion_kernel<<<dim3(K_INST + 16, B), dim3(512), 0, stream>>>(
        embed, order, seg_start, seg_cnt, fc_rev, cp_emb, cp_embT,
        seg_att, rep_sum, N);

    final_kernel<<<dim3(1), dim3(256), 0, stream>>>(
        fc_rev, seg_att, seg_cnt, pos_sum, neg_sum, rep_sum,
        cpv_cnt, noncp_cnt, valid_cnt, out, N, B);
}

// Round 14
// 98.295 us; speedup vs baseline: 1.1146x; 1.1146x over previous
//
#include <hip/hip_runtime.h>
#include <math.h>

#define K_INST 256
#define ATTRACTION_W 1.0f
#define REPULSION_W 1.0f
#define BETA_POS_W 1.0f
#define BETA_NEG_W 0.5f

typedef float f32x4 __attribute__((ext_vector_type(4)));
typedef int i32x4 __attribute__((ext_vector_type(4)));

__device__ inline float softplusf(float x) {
    return fmaxf(x, 0.f) + log1pf(expf(-fabsf(x)));
}

__device__ inline float waveReduceSumF(float v) {
    for (int o = 32; o; o >>= 1) v += __shfl_xor(v, o);
    return v;
}
__device__ inline int waveReduceSumI(int v) {
    for (int o = 32; o; o >>= 1) v += __shfl_xor(v, o);
    return v;
}

// 4 points per thread, vectorized. grid (N/1024, B), block 256.
__global__ void stats_kernel(const float* __restrict__ beta,
                             const int* __restrict__ sid,
                             const int* __restrict__ is_cp,
                             int* first_cp,
                             float* pos_sum, float* neg_sum,
                             int* cpv_cnt, int* noncp_cnt, int* valid_cnt,
                             int N) {
    int b = blockIdx.y;
    int base = (blockIdx.x * blockDim.x + threadIdx.x) * 4;
    const float* betaB = beta + (size_t)b * N;
    const int* sidB = sid + (size_t)b * N;
    const int* cpB = is_cp + (size_t)b * N;

    i32x4 s4 = *(const i32x4*)(sidB + base);
    i32x4 c4 = *(const i32x4*)(cpB + base);
    f32x4 x4 = *(const f32x4*)(betaB + base);

    float pos = 0.f, neg = 0.f;
    int c_cpv = 0, c_non = 0, c_val = 0;
    #pragma unroll
    for (int e = 0; e < 4; ++e) {
        int s = s4[e], cp = c4[e];
        float x = x4[e];
        bool valid = s >= 0;
        bool cpv = cp && valid;
        if (cpv) {
            pos += softplusf(-x);
            c_cpv++;
            atomicMin(&first_cp[b * K_INST + s], base + e);
        }
        if (!cp) {
            neg += softplusf(x);
            c_non++;
        }
        c_val += valid ? 1 : 0;
    }

    __shared__ float sf[2][4];
    __shared__ int si[3][4];
    pos = waveReduceSumF(pos);
    neg = waveReduceSumF(neg);
    c_cpv = waveReduceSumI(c_cpv);
    c_non = waveReduceSumI(c_non);
    c_val = waveReduceSumI(c_val);
    int wave = threadIdx.x >> 6, lane = threadIdx.x & 63;
    if (lane == 0) {
        sf[0][wave] = pos; sf[1][wave] = neg;
        si[0][wave] = c_cpv; si[1][wave] = c_non; si[2][wave] = c_val;
    }
    __syncthreads();
    if (threadIdx.x == 0) {
        float p = sf[0][0] + sf[0][1] + sf[0][2] + sf[0][3];
        float n = sf[1][0] + sf[1][1] + sf[1][2] + sf[1][3];
        int a = si[0][0] + si[0][1] + si[0][2] + si[0][3];
        int c = si[1][0] + si[1][1] + si[1][2] + si[1][3];
        int v = si[2][0] + si[2][1] + si[2][2] + si[2][3];
        if (p != 0.f) atomicAdd(&pos_sum[b], p);
        if (n != 0.f) atomicAdd(&neg_sum[b], n);
        if (a) atomicAdd(&cpv_cnt[b], a);
        if (c) atomicAdd(&noncp_cnt[b], c);
        if (v) atomicAdd(&valid_cnt[b], v);
    }
}

// one block per (k, b), 64 threads. writes row + transposed scatter.
__global__ void gather_kernel(const float* __restrict__ embed,
                              const int* __restrict__ first_cp,
                              float* __restrict__ cp_emb,
                              float* __restrict__ cp_embT, int N) {
    int b = blockIdx.y;
    int k = blockIdx.x;
    int src = first_cp[b * K_INST + k];
    if (src >= N) src = N - 1;
    int lane = threadIdx.x;
    const float* embB = embed + (size_t)b * N * 256;
    f32x4 v = ((const f32x4*)(embB + (size_t)src * 256))[lane];
    ((f32x4*)(cp_emb + ((size_t)b * K_INST + k) * 256))[lane] = v;
    float* T = cp_embT + (size_t)b * K_INST * 256;
    int d = lane * 4;
    T[(size_t)(d + 0) * 256 + k] = v[0];
    T[(size_t)(d + 1) * 256 + k] = v[1];
    T[(size_t)(d + 2) * 256 + k] = v[2];
    T[(size_t)(d + 3) * 256 + k] = v[3];
}

// fused: blockIdx.x < 32 -> repulsion; else attraction.
// embed/sid loads NONTEMPORAL so the stream doesn't evict cp_emb from L2/L3.
__global__ void attraction_repulsion_kernel(
        const float* __restrict__ embed,
        const int* __restrict__ sid,
        const int* __restrict__ first_cp,
        const float* __restrict__ cp_emb,
        const float* __restrict__ cp_embT,
        float* seg_sum, int* seg_cnt, float* rep_sum,
        int N, int atr_blocks) {
    int b = blockIdx.y;
    __shared__ __align__(16) char smem[8448];   // union: srow | s_sum+s_cnt
    __shared__ float sf[4];

    const float* cpB = cp_emb + (size_t)b * K_INST * 256;
    const int* fcB = first_cp + b * K_INST;

    if (blockIdx.x < 32) {
        // ---------------- repulsion ----------------
        float (*srow)[264] = (float(*)[264])smem;
        int i0 = blockIdx.x * 8;
        const float* T = cp_embT + (size_t)b * K_INST * 256;
        {
            int r = threadIdx.x >> 5, cc = (threadIdx.x & 31) * 8;
            f32x4 a = *(const f32x4*)(cpB + (size_t)(i0 + r) * 256 + cc);
            f32x4 bv = *(const f32x4*)(cpB + (size_t)(i0 + r) * 256 + cc + 4);
            srow[r][cc + 0] = a[0]; srow[r][cc + 1] = a[1];
            srow[r][cc + 2] = a[2]; srow[r][cc + 3] = a[3];
            srow[r][cc + 4] = bv[0]; srow[r][cc + 5] = bv[1];
            srow[r][cc + 6] = bv[2]; srow[r][cc + 7] = bv[3];
        }
        __syncthreads();

        int j = threadIdx.x;
        bool has_j = fcB[j] < N;
        float acc[8] = {0.f, 0.f, 0.f, 0.f, 0.f, 0.f, 0.f, 0.f};
        for (int d = 0; d < 256; d += 2) {
            float v0 = T[(size_t)d * 256 + j];
            float v1 = T[(size_t)(d + 1) * 256 + j];
            #pragma unroll
            for (int r = 0; r < 8; ++r) {
                float f0 = srow[r][d] - v0;
                float f1 = srow[r][d + 1] - v1;
                acc[r] += f0 * f0 + f1 * f1;
            }
        }
        float val = 0.f;
        #pragma unroll
        for (int r = 0; r < 8; ++r) {
            bool has_i = fcB[i0 + r] < N;
            if (has_i && has_j) val += expf(-acc[r]);
        }
        val = waveReduceSumF(val);
        int wave = threadIdx.x >> 6, lane = threadIdx.x & 63;
        if (lane == 0) sf[wave] = val;
        __syncthreads();
        if (threadIdx.x == 0)
            atomicAdd(&rep_sum[b], sf[0] + sf[1] + sf[2] + sf[3]);
    } else {
        // ---------------- attraction ----------------
        float* s_sum = (float*)smem;
        int* s_cnt = (int*)(smem + 1024);
        for (int k = threadIdx.x; k < K_INST; k += blockDim.x) { s_sum[k] = 0.f; s_cnt[k] = 0; }
        __syncthreads();

        int bx = blockIdx.x - 32;
        int lane = threadIdx.x & 63;
        int wid = bx * 4 + (threadIdx.x >> 6);
        int stride = atr_blocks * 4 * 8;

        const float* embB = embed + (size_t)b * N * 256;
        const int* sidB = sid + (size_t)b * N;

        int i = wid * 8;
        i32x4 sa = {0, 0, 0, 0}, sb = {0, 0, 0, 0};
        if (i < N) {
            sa = __builtin_nontemporal_load((const i32x4*)(sidB + i));
            sb = __builtin_nontemporal_load((const i32x4*)(sidB + i + 4));
        }
        while (i < N) {
            int ss[8] = {sa[0], sa[1], sa[2], sa[3], sb[0], sb[1], sb[2], sb[3]};

            // streaming embed loads: nontemporal (evict-first), keep L2/L3 for cp
            f32x4 e[8];
            #pragma unroll
            for (int j = 0; j < 8; ++j)
                e[j] = __builtin_nontemporal_load(
                    (const f32x4*)(embB + (size_t)(i + j) * 256 + lane * 4));
            // cp rows: normal cached loads (L2-resident)
            f32x4 c[8];
            #pragma unroll
            for (int j = 0; j < 8; ++j) {
                int sc = ss[j] < 0 ? 0 : ss[j];
                c[j] = *(const f32x4*)(cpB + (size_t)sc * 256 + lane * 4);
            }
            // prefetch next iteration's sid
            int inext = i + stride;
            i32x4 na = {0, 0, 0, 0}, nb = {0, 0, 0, 0};
            if (inext < N) {
                na = __builtin_nontemporal_load((const i32x4*)(sidB + inext));
                nb = __builtin_nontemporal_load((const i32x4*)(sidB + inext + 4));
            }

            float v[8];
            #pragma unroll
            for (int j = 0; j < 8; ++j) {
                float d0 = e[j][0] - c[j][0], d1 = e[j][1] - c[j][1];
                float d2 = e[j][2] - c[j][2], d3 = e[j][3] - c[j][3];
                v[j] = d0 * d0 + d1 * d1 + d2 * d2 + d3 * d3;
            }
            #pragma unroll
            for (int j = 0; j < 8; ++j) v[j] = waveReduceSumF(v[j]);
            if (lane == 0) {
                #pragma unroll
                for (int j = 0; j < 8; ++j) {
                    if (ss[j] >= 0) {   // no-CP segments discarded in final gate
                        atomicAdd(&s_sum[ss[j]], v[j]);
                        atomicAdd(&s_cnt[ss[j]], 1);
                    }
                }
            }
            sa = na; sb = nb;
            i = inext;
        }
        __syncthreads();
        for (int k = threadIdx.x; k < K_INST; k += blockDim.x) {
            if (s_cnt[k]) {
                atomicAdd(&seg_sum[b * K_INST + k], s_sum[k]);
                atomicAdd(&seg_cnt[b * K_INST + k], s_cnt[k]);
            }
        }
    }
}

__global__ void final_kernel(const int* __restrict__ first_cp,
                             const float* __restrict__ seg_sum,
                             const int* __restrict__ seg_cnt,
                             const float* __restrict__ pos_sum,
                             const float* __restrict__ neg_sum,
                             const float* __restrict__ rep_sum,
                             const int* __restrict__ cpv_cnt,
                             const int* __restrict__ noncp_cnt,
                             const int* __restrict__ valid_cnt,
                             float* out, int N, int B) {
    __shared__ float s_att[4];
    __shared__ int s_m[4];
    float loss_sum = 0.f;
    int ok_cnt = 0;
    int wave = threadIdx.x >> 6, lane = threadIdx.x & 63;
    for (int b = 0; b < B; ++b) {
        int k = threadIdx.x;
        int fc = first_cp[b * K_INST + k];
        int has = (fc < N) ? 1 : 0;
        int cnt = seg_cnt[b * K_INST + k];
        float att = (has && cnt > 0) ? (seg_sum[b * K_INST + k] / (float)cnt) : 0.f;
        att = waveReduceSumF(att);
        has = waveReduceSumI(has);
        if (lane == 0) { s_att[wave] = att; s_m[wave] = has; }
        __syncthreads();
        if (threadIdx.x == 0) {
            float attraction = (s_att[0] + s_att[1] + s_att[2] + s_att[3]) * ATTRACTION_W;
            int M = s_m[0] + s_m[1] + s_m[2] + s_m[3];
            float pos = pos_sum[b] / fmaxf((float)cpv_cnt[b], 1.f);
            float neg = neg_sum[b] / fmaxf((float)noncp_cnt[b], 1.f);
            float beta_loss = BETA_POS_W * pos + BETA_NEG_W * neg;
            float rep = 0.f;
            if (M > 1) {
                float mm = (float)M * (float)M;
                rep = (rep_sum[b] / fmaxf(mm, 1.f)) * REPULSION_W;
            }
            float loss = beta_loss + attraction + rep;
            bool ok = (valid_cnt[b] > 0) && (cpv_cnt[b] > 0);
            if (ok) { loss_sum += loss; ok_cnt += 1; }
        }
        __syncthreads();
    }
    if (threadIdx.x == 0) {
        out[0] = (ok_cnt > 0) ? (loss_sum / (float)ok_cnt) : 0.f;
    }
}

extern "C" void kernel_launch(void* const* d_in, const int* in_sizes, int n_in,
                              void* d_out, int out_size, void* d_ws, size_t ws_size,
                              hipStream_t stream) {
    const float* beta  = (const float*)d_in[0];
    const float* embed = (const float*)d_in[1];
    const int* sid     = (const int*)d_in[2];
    const int* is_cp   = (const int*)d_in[3];
    float* out = (float*)d_out;

    const int N = 65536;
    const int B = in_sizes[0] / N;
    (void)n_in; (void)out_size; (void)ws_size;

    char* ws = (char*)d_ws;
    int*   first_cp  = (int*)(ws + 0);
    float* seg_sum   = (float*)(ws + 4096);
    int*   seg_cnt   = (int*)(ws + 8192);
    float* pos_sum   = (float*)(ws + 12288);
    float* neg_sum   = (float*)(ws + 12352);
    float* rep_sum   = (float*)(ws + 12416);
    int*   cpv_cnt   = (int*)(ws + 12480);
    int*   noncp_cnt = (int*)(ws + 12544);
    int*   valid_cnt = (int*)(ws + 12608);
    float* cp_emb    = (float*)(ws + 16384);
    float* cp_embT   = (float*)(ws + 16384 + (size_t)B * K_INST * 256 * 4);

    // init via async memsets (graph-capturable): first_cp = 0x7F7F7F7F (> N),
    // accumulators = 0
    hipMemsetAsync(first_cp, 0x7F, (size_t)B * K_INST * 4, stream);
    hipMemsetAsync(ws + 4096, 0, 12288, stream);

    stats_kernel<<<dim3(N / 1024, B), dim3(256), 0, stream>>>(
        beta, sid, is_cp, first_cp, pos_sum, neg_sum,
        cpv_cnt, noncp_cnt, valid_cnt, N);

    gather_kernel<<<dim3(K_INST, B), dim3(64), 0, stream>>>(
        embed, first_cp, cp_emb, cp_embT, N);

    const int atr_blocks = 512;
    attraction_repulsion_kernel<<<dim3(32 + atr_blocks, B), dim3(256), 0, stream>>>(
        embed, sid, first_cp, cp_emb, cp_embT,
        seg_sum, seg_cnt, rep_sum, N, atr_blocks);

    final_kernel<<<dim3(1), dim3(256), 0, stream>>>(
        first_cp, seg_sum, seg_cnt, pos_sum, neg_sum, rep_sum,
        cpv_cnt, noncp_cnt, valid_cnt, out, N, B);
}